// Round 2
// baseline (32007.962 us; speedup 1.0000x reference)
//
#include <hip/hip_runtime.h>
#include <math.h>

#define L_   4
#define H_   8
#define D_   512
#define DH   64
#define DFF_ 2048
#define V_   8000
#define B_   16
#define SENC 128
#define T_   32
#define TP1  33
#define NEGV -1e9f
#define EPSV 1e-6f
#define SQRTD 22.627416997969522f   // sqrt(512)
#define XSZ  ((size_t)TP1 * B_ * D_)   // 270336 floats
#define DD   ((size_t)D_ * D_)

// ---------------------------------------------------------------------------
// fp32 GEMM, 64x64 tile, 256 threads (4x4 micro-tile), double-buffered LDS,
// float4 global loads. k-range = [blockIdx.z*kchunk, +kchunk); block z
// writes C + z*pstride. tmode==1: KcT transpose epilogue.
// ---------------------------------------------------------------------------
__global__ __launch_bounds__(256) void gemm32_k(
    const float* __restrict__ A, const float* __restrict__ W,
    const float* __restrict__ bias, float* __restrict__ C,
    int M, int N, int K, int kchunk, size_t pstride, int relu, int tmode)
{
    __shared__ __align__(16) float As[2][16][68];
    __shared__ __align__(16) float Bs[2][16][68];
    int tid = threadIdx.x;
    int tx = tid & 15, ty = tid >> 4;          // 16 cols x4, 16 rows x4
    int m0 = blockIdx.y * 64, n0 = blockIdx.x * 64;
    int kbeg = blockIdx.z * kchunk;
    int niter = kchunk >> 4;
    C += (size_t)blockIdx.z * pstride;
    int am = tid >> 2, aseg = tid & 3;         // A loader: 64 rows x 4 k-segs
    int bk = tid >> 4, bc4 = (tid & 15) * 4;   // B loader: 16 k x 64 n
    float4 aReg = make_float4(0.f, 0.f, 0.f, 0.f), bReg;
    {
        int gm = m0 + am;
        if (gm < M) aReg = *(const float4*)&A[(size_t)gm * K + kbeg + aseg * 4];
        bReg = *(const float4*)&W[(size_t)(kbeg + bk) * N + n0 + bc4];
    }
    As[0][aseg * 4 + 0][am] = aReg.x;
    As[0][aseg * 4 + 1][am] = aReg.y;
    As[0][aseg * 4 + 2][am] = aReg.z;
    As[0][aseg * 4 + 3][am] = aReg.w;
    *(float4*)&Bs[0][bk][bc4] = bReg;
    __syncthreads();
    float acc[4][4] = {};
    for (int it = 0; it < niter; it++) {
        int cur = it & 1;
        if (it + 1 < niter) {
            int k0 = kbeg + (it + 1) * 16;
            int gm = m0 + am;
            aReg = make_float4(0.f, 0.f, 0.f, 0.f);
            if (gm < M) aReg = *(const float4*)&A[(size_t)gm * K + k0 + aseg * 4];
            bReg = *(const float4*)&W[(size_t)(k0 + bk) * N + n0 + bc4];
        }
        #pragma unroll
        for (int kk = 0; kk < 16; kk++) {
            float4 a4 = *(const float4*)&As[cur][kk][ty * 4];
            float4 b4 = *(const float4*)&Bs[cur][kk][tx * 4];
            acc[0][0] += a4.x * b4.x; acc[0][1] += a4.x * b4.y;
            acc[0][2] += a4.x * b4.z; acc[0][3] += a4.x * b4.w;
            acc[1][0] += a4.y * b4.x; acc[1][1] += a4.y * b4.y;
            acc[1][2] += a4.y * b4.z; acc[1][3] += a4.y * b4.w;
            acc[2][0] += a4.z * b4.x; acc[2][1] += a4.z * b4.y;
            acc[2][2] += a4.z * b4.z; acc[2][3] += a4.z * b4.w;
            acc[3][0] += a4.w * b4.x; acc[3][1] += a4.w * b4.y;
            acc[3][2] += a4.w * b4.z; acc[3][3] += a4.w * b4.w;
        }
        if (it + 1 < niter) {
            int nxt = 1 - cur;
            As[nxt][aseg * 4 + 0][am] = aReg.x;
            As[nxt][aseg * 4 + 1][am] = aReg.y;
            As[nxt][aseg * 4 + 2][am] = aReg.z;
            As[nxt][aseg * 4 + 3][am] = aReg.w;
            *(float4*)&Bs[nxt][bk][bc4] = bReg;
        }
        __syncthreads();
    }
    #pragma unroll
    for (int i = 0; i < 4; i++) {
        int gm = m0 + ty * 4 + i;
        if (gm >= M) continue;
        if (tmode == 1) {
            #pragma unroll
            for (int j = 0; j < 4; j++) {
                int gn = n0 + tx * 4 + j;
                float vv = acc[i][j];
                if (bias) vv += bias[gn];
                if (relu) vv = fmaxf(vv, 0.f);
                C[(size_t)(gm >> 7) * 65536 + (size_t)gn * SENC + (gm & 127)] = vv;
            }
        } else {
            int gn = n0 + tx * 4;
            float4 o;
            o.x = acc[i][0]; o.y = acc[i][1]; o.z = acc[i][2]; o.w = acc[i][3];
            if (bias) {
                o.x += bias[gn + 0]; o.y += bias[gn + 1];
                o.z += bias[gn + 2]; o.w += bias[gn + 3];
            }
            if (relu) {
                o.x = fmaxf(o.x, 0.f); o.y = fmaxf(o.y, 0.f);
                o.z = fmaxf(o.z, 0.f); o.w = fmaxf(o.w, 0.f);
            }
            *(float4*)&C[(size_t)gm * N + gn] = o;
        }
    }
}

// ---------------------------------------------------------------------------
// Fused QKV: blockIdx.x: sel = x>>3 in {q,k,v}, n-tile = x&7. N=K=512.
// 64x64 tile, 4x4 micro. q,v row-major; k TRANSPOSED:
// kT[((b*8+h)*64+d)*33 + p], gm=p*16+b, gn=h*64+d.
// ---------------------------------------------------------------------------
__global__ __launch_bounds__(256) void gemm_qkv_k(
    const float* __restrict__ A, const float* __restrict__ W0,
    const float* __restrict__ W1, const float* __restrict__ W2,
    float* __restrict__ Cb, int M)
{
    __shared__ __align__(16) float As[2][16][68];
    __shared__ __align__(16) float Bs[2][16][68];
    int sel = blockIdx.x >> 3;
    const float* W = (sel == 0) ? W0 : ((sel == 1) ? W1 : W2);
    float* C = Cb + (size_t)sel * XSZ;
    int tid = threadIdx.x;
    int tx = tid & 15, ty = tid >> 4;
    int m0 = blockIdx.y * 64, n0 = (blockIdx.x & 7) * 64;
    int am = tid >> 2, aseg = tid & 3;
    int bk = tid >> 4, bc4 = (tid & 15) * 4;
    float4 aReg = make_float4(0.f, 0.f, 0.f, 0.f), bReg;
    {
        int gm = m0 + am;
        if (gm < M) aReg = *(const float4*)&A[(size_t)gm * D_ + aseg * 4];
        bReg = *(const float4*)&W[(size_t)bk * D_ + n0 + bc4];
    }
    As[0][aseg * 4 + 0][am] = aReg.x;
    As[0][aseg * 4 + 1][am] = aReg.y;
    As[0][aseg * 4 + 2][am] = aReg.z;
    As[0][aseg * 4 + 3][am] = aReg.w;
    *(float4*)&Bs[0][bk][bc4] = bReg;
    __syncthreads();
    float acc[4][4] = {};
    for (int it = 0; it < 32; it++) {
        int cur = it & 1;
        if (it + 1 < 32) {
            int k0 = (it + 1) * 16;
            int gm = m0 + am;
            aReg = make_float4(0.f, 0.f, 0.f, 0.f);
            if (gm < M) aReg = *(const float4*)&A[(size_t)gm * D_ + k0 + aseg * 4];
            bReg = *(const float4*)&W[(size_t)(k0 + bk) * D_ + n0 + bc4];
        }
        #pragma unroll
        for (int kk = 0; kk < 16; kk++) {
            float4 a4 = *(const float4*)&As[cur][kk][ty * 4];
            float4 b4 = *(const float4*)&Bs[cur][kk][tx * 4];
            acc[0][0] += a4.x * b4.x; acc[0][1] += a4.x * b4.y;
            acc[0][2] += a4.x * b4.z; acc[0][3] += a4.x * b4.w;
            acc[1][0] += a4.y * b4.x; acc[1][1] += a4.y * b4.y;
            acc[1][2] += a4.y * b4.z; acc[1][3] += a4.y * b4.w;
            acc[2][0] += a4.z * b4.x; acc[2][1] += a4.z * b4.y;
            acc[2][2] += a4.z * b4.z; acc[2][3] += a4.z * b4.w;
            acc[3][0] += a4.w * b4.x; acc[3][1] += a4.w * b4.y;
            acc[3][2] += a4.w * b4.z; acc[3][3] += a4.w * b4.w;
        }
        if (it + 1 < 32) {
            int nxt = 1 - cur;
            As[nxt][aseg * 4 + 0][am] = aReg.x;
            As[nxt][aseg * 4 + 1][am] = aReg.y;
            As[nxt][aseg * 4 + 2][am] = aReg.z;
            As[nxt][aseg * 4 + 3][am] = aReg.w;
            *(float4*)&Bs[nxt][bk][bc4] = bReg;
        }
        __syncthreads();
    }
    #pragma unroll
    for (int i = 0; i < 4; i++) {
        int gm = m0 + ty * 4 + i;
        if (gm >= M) continue;
        if (sel == 1) {
            #pragma unroll
            for (int j = 0; j < 4; j++) {
                int gn = n0 + tx * 4 + j;
                C[(size_t)(gm & 15) * 16896 + (size_t)gn * TP1 + (gm >> 4)] =
                    acc[i][j];
            }
        } else {
            float4 o;
            o.x = acc[i][0]; o.y = acc[i][1]; o.z = acc[i][2]; o.w = acc[i][3];
            *(float4*)&C[(size_t)gm * D_ + n0 + tx * 4] = o;
        }
    }
}

// ---------------------------------------------------------------------------
__global__ void init_k(int* __restrict__ tokens, int* __restrict__ done,
                       float* __restrict__ cmask, const float* __restrict__ pm)
{
    int tid = threadIdx.x + blockIdx.x * 256;
    if (tid < B_ * TP1) tokens[tid] = ((tid % TP1) == 0) ? 1 : 0;
    if (tid < B_) done[tid] = 0;
    if (tid < B_ * SENC) cmask[tid] = pm[tid] * NEGV;
}

// ---------------------------------------------------------------------------
// Sinusoid table, computed once: pe[p*D_+d].
// ---------------------------------------------------------------------------
__global__ __launch_bounds__(256) void pe_k(float* __restrict__ pe)
{
    int p = blockIdx.x;
    for (int d = threadIdx.x; d < D_; d += 256) {
        float fd = (float)(2 * (d / 2)) / (float)D_;
        float ang = (float)p / powf(10000.f, fd);
        pe[(size_t)p * D_ + d] = (d & 1) ? cosf(ang) : sinf(ang);
    }
}

// ---------------------------------------------------------------------------
// Transpose 12 512x512 matrices (wo[0..3], cwq[0..3], cwo[0..3]) into dst:
// dst[z][m][k] = src_z[k][m]. LDS-tiled 32x32.
// ---------------------------------------------------------------------------
__global__ __launch_bounds__(256) void transpose_k(
    const float* __restrict__ wo, const float* __restrict__ cwq,
    const float* __restrict__ cwo, float* __restrict__ dst)
{
    __shared__ float tile[32][33];
    int z = blockIdx.z;
    int sel = z >> 2, l = z & 3;
    const float* src = (sel == 0) ? wo : ((sel == 1) ? cwq : cwo);
    src += (size_t)l * DD;
    float* d = dst + (size_t)z * DD;
    int x0 = blockIdx.x * 32, y0 = blockIdx.y * 32;
    int lx = threadIdx.x & 31, ly = threadIdx.x >> 5;   // 32 x 8
    #pragma unroll
    for (int r = 0; r < 32; r += 8)
        tile[ly + r][lx] = src[(size_t)(y0 + ly + r) * D_ + x0 + lx];
    __syncthreads();
    #pragma unroll
    for (int r = 0; r < 32; r += 8)
        d[(size_t)(x0 + ly + r) * D_ + y0 + lx] = tile[lx][ly + r];
}

// ---------------------------------------------------------------------------
// Fused embed + (for the p==t block) argmax of previous step's logits.
// Token update is done by exactly one block per batch (p==t), so no races.
// ---------------------------------------------------------------------------
__global__ __launch_bounds__(256) void embed_k(
    const float* __restrict__ embed, int* __restrict__ tokens,
    float* __restrict__ x, const float* __restrict__ pe,
    const float* __restrict__ cand_v, const int* __restrict__ cand_i,
    int* __restrict__ done, int t)
{
    int p = blockIdx.x;
    int b = blockIdx.y;
    int tid = threadIdx.x;
    __shared__ float sv[128];
    __shared__ int si[128];
    __shared__ int stok;
    if (p == t && t > 0) {
        if (tid < 128) {
            float val = -1e30f; int idx = 0x7fffffff;
            if (tid < 125) {
                val = cand_v[(size_t)b * 125 + tid];
                idx = cand_i[(size_t)b * 125 + tid];
            }
            sv[tid] = val; si[tid] = idx;
        }
        __syncthreads();
        for (int s = 64; s; s >>= 1) {
            if (tid < s) {
                float ov = sv[tid + s]; int oi = si[tid + s];
                if (ov > sv[tid] || (ov == sv[tid] && oi < si[tid])) {
                    sv[tid] = ov; si[tid] = oi;
                }
            }
            __syncthreads();
        }
        if (tid == 0) {
            int best = si[0];
            int dn = done[b] | (best == 2 ? 1 : 0);
            done[b] = dn;
            int tk = dn ? 0 : best;
            tokens[b * TP1 + t] = tk;
            stok = tk;
        }
        __syncthreads();
    }
    int tok = (p == t && t > 0) ? stok : tokens[b * TP1 + p];
    const float* e = embed + (size_t)tok * D_;
    const float* pr = pe + (size_t)p * D_;
    float* xr = x + ((size_t)p * B_ + b) * D_;
    int c0 = tid * 2;
    float2 ev = *(const float2*)&e[c0];
    float2 pv = *(const float2*)&pr[c0];
    float2 o;
    o.x = ev.x * SQRTD + pv.x;
    o.y = ev.y * SQRTD + pv.y;
    *(float2*)&xr[c0] = o;
}

// ---------------------------------------------------------------------------
__device__ __forceinline__ float block_sum(float s) {
    __shared__ float red[4];
    #pragma unroll
    for (int off = 32; off; off >>= 1) s += __shfl_xor(s, off);
    if ((threadIdx.x & 63) == 0) red[threadIdx.x >> 6] = s;
    __syncthreads();
    float tot = red[0] + red[1] + red[2] + red[3];
    __syncthreads();
    return tot;
}

// ---------------------------------------------------------------------------
// MEGA: self-attn + wo + LN + cross(q-proj, attn, cwo) + LN. Block per row.
// q row-major; kT [(b*8+h)*64+d][33]; v row-major; KcT [(b*8+h)*64+d][128];
// Vc row-major. lg/lb point at ln[l][0]; second LN uses +D_ offset.
// wt==1: wo/cwq/cwo are TRANSPOSED [col][k] -> per-thread contiguous float4
// streams (deep prefetch, no 2KB-stride latency chains). Same summation
// order as the row-major path -> bitwise-identical numerics.
// ---------------------------------------------------------------------------
__global__ __launch_bounds__(256) void attn_mega_k(
    const float* __restrict__ q, const float* __restrict__ kT,
    const float* __restrict__ v, const float* __restrict__ wo,
    const float* __restrict__ KcT, const float* __restrict__ Vc,
    const float* __restrict__ cmask, const float* __restrict__ cwq,
    const float* __restrict__ cwo, float* __restrict__ x,
    const float* __restrict__ lg, const float* __restrict__ lb, int P, int wt)
{
    int r = blockIdx.x, b = r & 15;
    int tid = threadIdx.x;
    int c0 = tid * 2;
    __shared__ float xs[D_], arow[D_];
    __shared__ float scs[H_][SENC];
    __shared__ float inv[H_];
    // ---- self scores: thread (h=tid>>5, kp=tid&31)
    {
        int kp = tid & 31, h = tid >> 5;
        float acc = 0.f;
        if (kp < P) {
            const float* qr = q + (size_t)r * D_ + h * 64;
            const float* kb = kT + ((size_t)(b * 8 + h) * 64) * TP1 + kp;
            #pragma unroll 8
            for (int d = 0; d < 64; d++) acc += qr[d] * kb[(size_t)d * TP1];
        }
        scs[h][kp] = acc * 0.125f;
    }
    __syncthreads();
    if (tid < 8) {
        float mx = -1e30f;
        for (int j = 0; j < P; j++) mx = fmaxf(mx, scs[tid][j]);
        float sum = 0.f;
        for (int j = 0; j < P; j++) {
            float e = expf(scs[tid][j] - mx);
            scs[tid][j] = e;
            sum += e;
        }
        inv[tid] = 1.f / sum;
    }
    __syncthreads();
    // ---- weighted V -> arow
    {
        int h = c0 >> 6;
        float o0 = 0.f, o1 = 0.f;
        for (int j = 0; j < P; j++) {
            float2 vv = *(const float2*)&v[((size_t)j * B_ + b) * D_ + c0];
            float w = scs[h][j];
            o0 += w * vv.x; o1 += w * vv.y;
        }
        arow[c0]     = o0 * inv[h];
        arow[c0 + 1] = o1 * inv[h];
    }
    __syncthreads();
    // ---- wo out-proj + residual + LN -> xs
    {
        float2 xv = *(const float2*)&x[(size_t)r * D_ + c0];
        float v0 = xv.x, v1 = xv.y;
        if (wt) {
            const float* wr0 = wo + (size_t)c0 * D_;
            const float* wr1 = wr0 + D_;
            #pragma unroll 8
            for (int k = 0; k < D_; k += 4) {
                float4 wa = *(const float4*)&wr0[k];
                float4 wb = *(const float4*)&wr1[k];
                float a0 = arow[k], a1 = arow[k + 1];
                float a2 = arow[k + 2], a3 = arow[k + 3];
                v0 += a0 * wa.x; v0 += a1 * wa.y; v0 += a2 * wa.z; v0 += a3 * wa.w;
                v1 += a0 * wb.x; v1 += a1 * wb.y; v1 += a2 * wb.z; v1 += a3 * wb.w;
            }
        } else {
            #pragma unroll 8
            for (int k = 0; k < D_; k++) {
                float a = arow[k];
                float2 wv = *(const float2*)&wo[(size_t)k * D_ + c0];
                v0 += a * wv.x; v1 += a * wv.y;
            }
        }
        float mean = block_sum(v0 + v1) * (1.f / 512.f);
        float d0 = v0 - mean, d1 = v1 - mean;
        float var = block_sum(d0 * d0 + d1 * d1) * (1.f / 512.f);
        float rs = rsqrtf(var + EPSV);
        xs[c0]     = d0 * rs * lg[c0]     + lb[c0];
        xs[c0 + 1] = d1 * rs * lg[c0 + 1] + lb[c0 + 1];
    }
    __syncthreads();
    // ---- cross q-proj -> arow (reused as qrow)
    {
        float q0 = 0.f, q1 = 0.f;
        if (wt) {
            const float* wr0 = cwq + (size_t)c0 * D_;
            const float* wr1 = wr0 + D_;
            #pragma unroll 8
            for (int k = 0; k < D_; k += 4) {
                float4 wa = *(const float4*)&wr0[k];
                float4 wb = *(const float4*)&wr1[k];
                float a0 = xs[k], a1 = xs[k + 1];
                float a2 = xs[k + 2], a3 = xs[k + 3];
                q0 += a0 * wa.x; q0 += a1 * wa.y; q0 += a2 * wa.z; q0 += a3 * wa.w;
                q1 += a0 * wb.x; q1 += a1 * wb.y; q1 += a2 * wb.z; q1 += a3 * wb.w;
            }
        } else {
            #pragma unroll 8
            for (int k = 0; k < D_; k++) {
                float a = xs[k];
                float2 wv = *(const float2*)&cwq[(size_t)k * D_ + c0];
                q0 += a * wv.x; q1 += a * wv.y;
            }
        }
        arow[c0] = q0; arow[c0 + 1] = q1;
    }
    __syncthreads();
    // ---- cross scores: 4 (h,s) pairs per thread
    #pragma unroll
    for (int j = 0; j < 4; j++) {
        int idx = tid + j * 256;
        int h = idx >> 7, s = idx & 127;
        const float* kb = KcT + ((size_t)(b * 512 + h * 64)) * SENC + s;
        float acc = 0.f;
        #pragma unroll 8
        for (int d = 0; d < 64; d++) acc += arow[h * 64 + d] * kb[(size_t)d * SENC];
        scs[h][s] = acc * 0.125f + cmask[b * SENC + s];
    }
    __syncthreads();
    if (tid < 8) {
        float mx = -1e30f;
        for (int s = 0; s < SENC; s++) mx = fmaxf(mx, scs[tid][s]);
        float sum = 0.f;
        for (int s = 0; s < SENC; s++) {
            float e = expf(scs[tid][s] - mx);
            scs[tid][s] = e;
            sum += e;
        }
        inv[tid] = 1.f / sum;
    }
    __syncthreads();
    // ---- cross weighted V -> arow (qrow dead after score phase)
    {
        int h = c0 >> 6;
        float o0 = 0.f, o1 = 0.f;
        for (int s = 0; s < SENC; s++) {
            float2 vv = *(const float2*)&Vc[((size_t)b * SENC + s) * D_ + c0];
            float w = scs[h][s];
            o0 += w * vv.x; o1 += w * vv.y;
        }
        arow[c0]     = o0 * inv[h];
        arow[c0 + 1] = o1 * inv[h];
    }
    __syncthreads();
    // ---- cwo out-proj + residual(xs) + LN -> x
    {
        float v0 = xs[c0], v1 = xs[c0 + 1];
        if (wt) {
            const float* wr0 = cwo + (size_t)c0 * D_;
            const float* wr1 = wr0 + D_;
            #pragma unroll 8
            for (int k = 0; k < D_; k += 4) {
                float4 wa = *(const float4*)&wr0[k];
                float4 wb = *(const float4*)&wr1[k];
                float a0 = arow[k], a1 = arow[k + 1];
                float a2 = arow[k + 2], a3 = arow[k + 3];
                v0 += a0 * wa.x; v0 += a1 * wa.y; v0 += a2 * wa.z; v0 += a3 * wa.w;
                v1 += a0 * wb.x; v1 += a1 * wb.y; v1 += a2 * wb.z; v1 += a3 * wb.w;
            }
        } else {
            #pragma unroll 8
            for (int k = 0; k < D_; k++) {
                float a = arow[k];
                float2 wv = *(const float2*)&cwo[(size_t)k * D_ + c0];
                v0 += a * wv.x; v1 += a * wv.y;
            }
        }
        float mean = block_sum(v0 + v1) * (1.f / 512.f);
        float d0 = v0 - mean, d1 = v1 - mean;
        float var = block_sum(d0 * d0 + d1 * d1) * (1.f / 512.f);
        float rs = rsqrtf(var + EPSV);
        x[(size_t)r * D_ + c0]     = d0 * rs * lg[D_ + c0]     + lb[D_ + c0];
        x[(size_t)r * D_ + c0 + 1] = d1 * rs * lg[D_ + c0 + 1] + lb[D_ + c0 + 1];
    }
}

// ---------------------------------------------------------------------------
// x = LN(x + sum_parts (+ bias)) * g + b. One block per row.
// ---------------------------------------------------------------------------
__global__ __launch_bounds__(256) void ln_red_k(
    float* __restrict__ x, const float* __restrict__ parts, size_t pstride,
    int nparts, const float* __restrict__ bias,
    const float* __restrict__ gam, const float* __restrict__ bet)
{
    int r = blockIdx.x;
    float* xr = x + (size_t)r * D_;
    int tid = threadIdx.x;
    float v0 = xr[tid];
    float v1 = xr[tid + 256];
    for (int s = 0; s < nparts; s++) {
        const float* pr = parts + (size_t)s * pstride + (size_t)r * D_;
        v0 += pr[tid];
        v1 += pr[tid + 256];
    }
    if (bias) { v0 += bias[tid]; v1 += bias[tid + 256]; }
    float mean = block_sum(v0 + v1) * (1.f / 512.f);
    float d0 = v0 - mean, d1 = v1 - mean;
    float var = block_sum(d0 * d0 + d1 * d1) * (1.f / 512.f);
    float rs = rsqrtf(var + EPSV);
    xr[tid]       = d0 * rs * gam[tid] + bet[tid];
    xr[tid + 256] = d1 * rs * gam[tid + 256] + bet[tid + 256];
}

// ---------------------------------------------------------------------------
// logits -> per-block argmax candidates. Grid 125 x 256 thr = 64 cols x
// 4 K-chunks; wave 0 reduces its 64 cols per batch (val,idx).
// ---------------------------------------------------------------------------
__global__ __launch_bounds__(256) void logits_k(
    const float* __restrict__ x, const float* __restrict__ fcw,
    const float* __restrict__ fcb, float* __restrict__ cand_v,
    int* __restrict__ cand_i, int t)
{
    __shared__ float xs[B_][D_];
    __shared__ float red[4][64][B_];
    int tid = threadIdx.x;
    for (int i = tid; i < B_ * D_; i += 256) {
        int b = i >> 9, d = i & 511;
        xs[b][d] = x[((size_t)t * B_ + b) * D_ + d];
    }
    __syncthreads();
    int lane = tid & 63, ks = tid >> 6;
    int col = blockIdx.x * 64 + lane;
    float acc[B_] = {};
    int kb = ks * 128;
    for (int k = kb; k < kb + 128; k++) {
        float w = fcw[(size_t)k * V_ + col];
        #pragma unroll
        for (int b = 0; b < B_; b++) acc[b] += xs[b][k] * w;
    }
    #pragma unroll
    for (int b = 0; b < B_; b++) red[ks][lane][b] = acc[b];
    __syncthreads();
    if (ks == 0) {      // wave 0 only
        float bias = fcb[col];
        #pragma unroll
        for (int b = 0; b < B_; b++) {
            float val = red[0][lane][b] + red[1][lane][b]
                      + red[2][lane][b] + red[3][lane][b] + bias;
            int idx = col;
            #pragma unroll
            for (int off = 32; off; off >>= 1) {
                float ov = __shfl_down(val, off);
                int oi = __shfl_down(idx, off);
                if (ov > val || (ov == val && oi < idx)) { val = ov; idx = oi; }
            }
            if (lane == 0) {
                cand_v[(size_t)b * 125 + blockIdx.x] = val;
                cand_i[(size_t)b * 125 + blockIdx.x] = idx;
            }
        }
    }
}

// ---------------------------------------------------------------------------
// Final: one block per batch. Reduce step-31 candidates for token 32, copy
// the output row.
// ---------------------------------------------------------------------------
__global__ __launch_bounds__(128) void writeout_k(
    const int* __restrict__ tokens, const float* __restrict__ cand_v,
    const int* __restrict__ cand_i, const int* __restrict__ done,
    int* __restrict__ out)
{
    int b = blockIdx.x;
    int tid = threadIdx.x;
    __shared__ float sv[128];
    __shared__ int si[128];
    __shared__ int stok;
    float val = -1e30f; int idx = 0x7fffffff;
    if (tid < 125) {
        val = cand_v[(size_t)b * 125 + tid];
        idx = cand_i[(size_t)b * 125 + tid];
    }
    sv[tid] = val; si[tid] = idx;
    __syncthreads();
    for (int s = 64; s; s >>= 1) {
        if (tid < s) {
            float ov = sv[tid + s]; int oi = si[tid + s];
            if (ov > sv[tid] || (ov == sv[tid] && oi < si[tid])) {
                sv[tid] = ov; si[tid] = oi;
            }
        }
        __syncthreads();
    }
    if (tid == 0) {
        int best = si[0];
        int dn = done[b] | (best == 2 ? 1 : 0);
        stok = dn ? 0 : best;
    }
    __syncthreads();
    if (tid < T_)
        out[b * T_ + tid] = (tid == T_ - 1) ? stok : tokens[b * TP1 + tid + 1];
}

// ---------------------------------------------------------------------------
extern "C" void kernel_launch(void* const* d_in, const int* in_sizes, int n_in,
                              void* d_out, int out_size, void* d_ws, size_t ws_size,
                              hipStream_t stream)
{
    const float* enc   = (const float*)d_in[1];
    const float* pm    = (const float*)d_in[2];
    const float* embed = (const float*)d_in[3];
    const float* wq    = (const float*)d_in[4];
    const float* wk    = (const float*)d_in[5];
    const float* wv    = (const float*)d_in[6];
    const float* wo    = (const float*)d_in[7];
    const float* cwq   = (const float*)d_in[8];
    const float* cwk   = (const float*)d_in[9];
    const float* cwv   = (const float*)d_in[10];
    const float* cwo   = (const float*)d_in[11];
    const float* w1    = (const float*)d_in[12];
    const float* b1    = (const float*)d_in[13];
    const float* w2    = (const float*)d_in[14];
    const float* b2    = (const float*)d_in[15];
    const float* ln_g  = (const float*)d_in[16];
    const float* ln_b  = (const float*)d_in[17];
    const float* fcw   = (const float*)d_in[18];
    const float* fcb   = (const float*)d_in[19];

    float* ws = (float*)d_ws;
    size_t off = 0;
    float* x     = ws + off; off += XSZ;
    float* qkv   = ws + off; off += 3 * XSZ;      // q | kT | v
    float* parts = ws + off; off += 4 * XSZ;      // split-K partials
    float* ffnh  = ws + off; off += (size_t)TP1 * B_ * DFF_;
    float* cand_v= ws + off; off += (size_t)B_ * 125;
    float* KcT   = ws + off; off += (size_t)L_ * B_ * SENC * D_;
    float* Vc    = ws + off; off += (size_t)L_ * B_ * SENC * D_;
    float* cmask = ws + off; off += (size_t)B_ * SENC;
    float* pe    = ws + off; off += (size_t)TP1 * D_;
    int* cand_i  = (int*)(ws + off); off += (size_t)B_ * 125;
    int* tokens  = (int*)(ws + off); off += (B_ * TP1 + 63) & ~63;
    int* done    = (int*)(ws + off); off += 64;
    float* wT    = ws + off; off += 12 * DD;      // woT[4] | cwqT[4] | cwoT[4]
    int wtflag = (ws_size >= off * sizeof(float)) ? 1 : 0;

    init_k<<<8, 256, 0, stream>>>(tokens, done, cmask, pm);
    pe_k<<<TP1, 256, 0, stream>>>(pe);
    if (wtflag)
        transpose_k<<<dim3(16, 16, 12), 256, 0, stream>>>(wo, cwq, cwo, wT);

    // Precompute cross K (transposed) / V per layer
    const size_t KVL = (size_t)B_ * SENC * D_;
    for (int l = 0; l < L_; l++) {
        gemm32_k<<<dim3(8, (B_ * SENC) / 64), 256, 0, stream>>>(
            enc, cwk + (size_t)l * D_ * D_, nullptr, KcT + l * KVL,
            B_ * SENC, D_, D_, D_, 0, 0, 1);
        gemm32_k<<<dim3(8, (B_ * SENC) / 64), 256, 0, stream>>>(
            enc, cwv + (size_t)l * D_ * D_, nullptr, Vc + l * KVL,
            B_ * SENC, D_, D_, D_, 0, 0, 0);
    }

    for (int t = 0; t < T_; t++) {
        int P = t + 1;
        int M = P * B_;
        int mt = (M + 63) / 64;

        embed_k<<<dim3(P, B_), 256, 0, stream>>>(
            embed, tokens, x, pe, cand_v, cand_i, done, t);

        for (int l = 0; l < L_; l++) {
            const size_t lw = (size_t)l * D_ * D_;
            const float* woP  = wtflag ? wT + (size_t)(0 + l) * DD : wo + lw;
            const float* cwqP = wtflag ? wT + (size_t)(4 + l) * DD : cwq + lw;
            const float* cwoP = wtflag ? wT + (size_t)(8 + l) * DD : cwo + lw;
            gemm_qkv_k<<<dim3(24, mt), 256, 0, stream>>>(
                x, wq + lw, wk + lw, wv + lw, qkv, M);
            attn_mega_k<<<M, 256, 0, stream>>>(
                qkv, qkv + XSZ, qkv + 2 * XSZ, woP,
                KcT + l * KVL, Vc + l * KVL, cmask, cwqP, cwoP, x,
                ln_g + (size_t)(l * 3 + 0) * D_, ln_b + (size_t)(l * 3 + 0) * D_,
                P, wtflag);
            gemm32_k<<<dim3(32, mt), 256, 0, stream>>>(
                x, w1 + (size_t)l * D_ * DFF_, b1 + (size_t)l * DFF_, ffnh,
                M, DFF_, D_, D_, 0, 1, 0);
            gemm32_k<<<dim3(8, mt, 4), 256, 0, stream>>>(
                ffnh, w2 + (size_t)l * DFF_ * D_, nullptr, parts,
                M, D_, DFF_, 512, XSZ, 0, 0);
            ln_red_k<<<M, 256, 0, stream>>>(x, parts, XSZ, 4, b2 + (size_t)l * D_,
                ln_g + (size_t)(l * 3 + 2) * D_, ln_b + (size_t)(l * 3 + 2) * D_);
        }

        logits_k<<<V_ / 64, 256, 0, stream>>>(x, fcw, fcb, cand_v, cand_i, t);
    }

    writeout_k<<<B_, 128, 0, stream>>>(tokens, cand_v, cand_i, done, (int*)d_out);
}

// Round 3
// 24240.828 us; speedup vs baseline: 1.3204x; 1.3204x over previous
//
#include <hip/hip_runtime.h>
#include <math.h>

#define L_   4
#define H_   8
#define D_   512
#define DH   64
#define DFF_ 2048
#define V_   8000
#define B_   16
#define SENC 128
#define T_   32
#define TP1  33
#define NEGV -1e9f
#define EPSV 1e-6f
#define SQRTD 22.627416997969522f   // sqrt(512)
#define XSZ  ((size_t)TP1 * B_ * D_)   // 270336 floats

// ---------------------------------------------------------------------------
// fp32 GEMM, 32x64 tile, 256 threads (2x4 micro-tile), double-buffered LDS,
// float4 global loads. Latency regime: grids are <= ~CU count, so the 32-row
// tile's shorter per-block path beats 64x64 (measured: 64x64 cost +2.7ms).
// k-range = [blockIdx.z*kchunk, +kchunk); block z writes C + z*pstride.
// tmode==1: KcT transpose epilogue.
// ---------------------------------------------------------------------------
__global__ __launch_bounds__(256) void gemm32_k(
    const float* __restrict__ A, const float* __restrict__ W,
    const float* __restrict__ bias, float* __restrict__ C,
    int M, int N, int K, int kchunk, size_t pstride, int relu, int tmode)
{
    __shared__ __align__(16) float As[2][16][34];
    __shared__ __align__(16) float Bs[2][16][68];
    int tid = threadIdx.x;
    int tx = tid & 15, ty = tid >> 4;          // tx: 4 cols, ty: 2 rows
    int m0 = blockIdx.y * 32, n0 = blockIdx.x * 64;
    int kbeg = blockIdx.z * kchunk;
    int niter = kchunk >> 4;
    C += (size_t)blockIdx.z * pstride;
    int am = tid >> 2, aseg = tid & 3;         // A loader (tid<128)
    int bk = tid >> 4, bc4 = (tid & 15) * 4;   // B loader (all 256)
    float4 aReg = make_float4(0.f, 0.f, 0.f, 0.f), bReg;
    {
        int k0 = kbeg;
        if (tid < 128) {
            int gm = m0 + am;
            if (gm < M) aReg = *(const float4*)&A[(size_t)gm * K + k0 + aseg * 4];
        }
        bReg = *(const float4*)&W[(size_t)(k0 + bk) * N + n0 + bc4];
    }
    if (tid < 128) {
        As[0][aseg * 4 + 0][am] = aReg.x;
        As[0][aseg * 4 + 1][am] = aReg.y;
        As[0][aseg * 4 + 2][am] = aReg.z;
        As[0][aseg * 4 + 3][am] = aReg.w;
    }
    *(float4*)&Bs[0][bk][bc4] = bReg;
    __syncthreads();
    float acc[2][4] = {};
    for (int it = 0; it < niter; it++) {
        int cur = it & 1;
        if (it + 1 < niter) {
            int k0 = kbeg + (it + 1) * 16;
            if (tid < 128) {
                int gm = m0 + am;
                aReg = make_float4(0.f, 0.f, 0.f, 0.f);
                if (gm < M) aReg = *(const float4*)&A[(size_t)gm * K + k0 + aseg * 4];
            }
            bReg = *(const float4*)&W[(size_t)(k0 + bk) * N + n0 + bc4];
        }
        #pragma unroll
        for (int kk = 0; kk < 16; kk++) {
            float2 a2 = *(const float2*)&As[cur][kk][ty * 2];
            float4 b4 = *(const float4*)&Bs[cur][kk][tx * 4];
            acc[0][0] += a2.x * b4.x; acc[0][1] += a2.x * b4.y;
            acc[0][2] += a2.x * b4.z; acc[0][3] += a2.x * b4.w;
            acc[1][0] += a2.y * b4.x; acc[1][1] += a2.y * b4.y;
            acc[1][2] += a2.y * b4.z; acc[1][3] += a2.y * b4.w;
        }
        if (it + 1 < niter) {
            int nxt = 1 - cur;
            if (tid < 128) {
                As[nxt][aseg * 4 + 0][am] = aReg.x;
                As[nxt][aseg * 4 + 1][am] = aReg.y;
                As[nxt][aseg * 4 + 2][am] = aReg.z;
                As[nxt][aseg * 4 + 3][am] = aReg.w;
            }
            *(float4*)&Bs[nxt][bk][bc4] = bReg;
        }
        __syncthreads();
    }
    #pragma unroll
    for (int i = 0; i < 2; i++) {
        int gm = m0 + ty * 2 + i;
        if (gm >= M) continue;
        #pragma unroll
        for (int j = 0; j < 4; j++) {
            int gn = n0 + tx * 4 + j;
            float vv = acc[i][j];
            if (bias) vv += bias[gn];
            if (relu) vv = fmaxf(vv, 0.f);
            if (tmode == 1)
                C[(size_t)(gm >> 7) * 65536 + (size_t)gn * SENC + (gm & 127)] = vv;
            else
                C[(size_t)gm * N + gn] = vv;
        }
    }
}

// ---------------------------------------------------------------------------
// Fused QKV: blockIdx.x: sel = x>>3 in {q,k,v}, n-tile = x&7. N=K=512.
// q,v row-major; k TRANSPOSED: kT[((b*8+h)*64+d)*33 + p], gm=p*16+b, gn=h*64+d.
// ---------------------------------------------------------------------------
__global__ __launch_bounds__(256) void gemm_qkv_k(
    const float* __restrict__ A, const float* __restrict__ W0,
    const float* __restrict__ W1, const float* __restrict__ W2,
    float* __restrict__ Cb, int M)
{
    __shared__ __align__(16) float As[2][16][34];
    __shared__ __align__(16) float Bs[2][16][68];
    int sel = blockIdx.x >> 3;
    const float* W = (sel == 0) ? W0 : ((sel == 1) ? W1 : W2);
    float* C = Cb + (size_t)sel * XSZ;
    int tid = threadIdx.x;
    int tx = tid & 15, ty = tid >> 4;
    int m0 = blockIdx.y * 32, n0 = (blockIdx.x & 7) * 64;
    int am = tid >> 2, aseg = tid & 3;
    int bk = tid >> 4, bc4 = (tid & 15) * 4;
    float4 aReg = make_float4(0.f, 0.f, 0.f, 0.f), bReg;
    {
        if (tid < 128) {
            int gm = m0 + am;
            if (gm < M) aReg = *(const float4*)&A[(size_t)gm * D_ + aseg * 4];
        }
        bReg = *(const float4*)&W[(size_t)bk * D_ + n0 + bc4];
    }
    if (tid < 128) {
        As[0][aseg * 4 + 0][am] = aReg.x;
        As[0][aseg * 4 + 1][am] = aReg.y;
        As[0][aseg * 4 + 2][am] = aReg.z;
        As[0][aseg * 4 + 3][am] = aReg.w;
    }
    *(float4*)&Bs[0][bk][bc4] = bReg;
    __syncthreads();
    float acc[2][4] = {};
    for (int it = 0; it < 32; it++) {
        int cur = it & 1;
        if (it + 1 < 32) {
            int k0 = (it + 1) * 16;
            if (tid < 128) {
                int gm = m0 + am;
                aReg = make_float4(0.f, 0.f, 0.f, 0.f);
                if (gm < M) aReg = *(const float4*)&A[(size_t)gm * D_ + k0 + aseg * 4];
            }
            bReg = *(const float4*)&W[(size_t)(k0 + bk) * D_ + n0 + bc4];
        }
        #pragma unroll
        for (int kk = 0; kk < 16; kk++) {
            float2 a2 = *(const float2*)&As[cur][kk][ty * 2];
            float4 b4 = *(const float4*)&Bs[cur][kk][tx * 4];
            acc[0][0] += a2.x * b4.x; acc[0][1] += a2.x * b4.y;
            acc[0][2] += a2.x * b4.z; acc[0][3] += a2.x * b4.w;
            acc[1][0] += a2.y * b4.x; acc[1][1] += a2.y * b4.y;
            acc[1][2] += a2.y * b4.z; acc[1][3] += a2.y * b4.w;
        }
        if (it + 1 < 32) {
            int nxt = 1 - cur;
            if (tid < 128) {
                As[nxt][aseg * 4 + 0][am] = aReg.x;
                As[nxt][aseg * 4 + 1][am] = aReg.y;
                As[nxt][aseg * 4 + 2][am] = aReg.z;
                As[nxt][aseg * 4 + 3][am] = aReg.w;
            }
            *(float4*)&Bs[nxt][bk][bc4] = bReg;
        }
        __syncthreads();
    }
    #pragma unroll
    for (int i = 0; i < 2; i++) {
        int gm = m0 + ty * 2 + i;
        if (gm >= M) continue;
        #pragma unroll
        for (int j = 0; j < 4; j++) {
            int gn = n0 + tx * 4 + j;
            if (sel == 1)
                C[(size_t)(gm & 15) * 16896 + (size_t)gn * TP1 + (gm >> 4)] =
                    acc[i][j];
            else
                C[(size_t)gm * D_ + gn] = acc[i][j];
        }
    }
}

// ---------------------------------------------------------------------------
__global__ void init_k(int* __restrict__ tokens, int* __restrict__ done,
                       float* __restrict__ cmask, const float* __restrict__ pm)
{
    int tid = threadIdx.x + blockIdx.x * 256;
    if (tid < B_ * TP1) tokens[tid] = ((tid % TP1) == 0) ? 1 : 0;
    if (tid < B_) done[tid] = 0;
    if (tid < B_ * SENC) cmask[tid] = pm[tid] * NEGV;
}

// ---------------------------------------------------------------------------
// Sinusoid table, computed once: pe[p*D_+d].
// ---------------------------------------------------------------------------
__global__ __launch_bounds__(256) void pe_k(float* __restrict__ pe)
{
    int p = blockIdx.x;
    for (int d = threadIdx.x; d < D_; d += 256) {
        float fd = (float)(2 * (d / 2)) / (float)D_;
        float ang = (float)p / powf(10000.f, fd);
        pe[(size_t)p * D_ + d] = (d & 1) ? cosf(ang) : sinf(ang);
    }
}

// ---------------------------------------------------------------------------
// Fused embed + (for the p==t block) argmax of previous step's logits.
// Token update is done by exactly one block per batch (p==t), so no races.
// ---------------------------------------------------------------------------
__global__ __launch_bounds__(256) void embed_k(
    const float* __restrict__ embed, int* __restrict__ tokens,
    float* __restrict__ x, const float* __restrict__ pe,
    const float* __restrict__ cand_v, const int* __restrict__ cand_i,
    int* __restrict__ done, int t)
{
    int p = blockIdx.x;
    int b = blockIdx.y;
    int tid = threadIdx.x;
    __shared__ float sv[128];
    __shared__ int si[128];
    __shared__ int stok;
    if (p == t && t > 0) {
        if (tid < 128) {
            float val = -1e30f; int idx = 0x7fffffff;
            if (tid < 125) {
                val = cand_v[(size_t)b * 125 + tid];
                idx = cand_i[(size_t)b * 125 + tid];
            }
            sv[tid] = val; si[tid] = idx;
        }
        __syncthreads();
        for (int s = 64; s; s >>= 1) {
            if (tid < s) {
                float ov = sv[tid + s]; int oi = si[tid + s];
                if (ov > sv[tid] || (ov == sv[tid] && oi < si[tid])) {
                    sv[tid] = ov; si[tid] = oi;
                }
            }
            __syncthreads();
        }
        if (tid == 0) {
            int best = si[0];
            int dn = done[b] | (best == 2 ? 1 : 0);
            done[b] = dn;
            int tk = dn ? 0 : best;
            tokens[b * TP1 + t] = tk;
            stok = tk;
        }
        __syncthreads();
    }
    int tok = (p == t && t > 0) ? stok : tokens[b * TP1 + p];
    const float* e = embed + (size_t)tok * D_;
    const float* pr = pe + (size_t)p * D_;
    float* xr = x + ((size_t)p * B_ + b) * D_;
    int c0 = tid * 2;
    float2 ev = *(const float2*)&e[c0];
    float2 pv = *(const float2*)&pr[c0];
    float2 o;
    o.x = ev.x * SQRTD + pv.x;
    o.y = ev.y * SQRTD + pv.y;
    *(float2*)&xr[c0] = o;
}

// ---------------------------------------------------------------------------
__device__ __forceinline__ float block_sum(float s) {
    __shared__ float red[4];
    #pragma unroll
    for (int off = 32; off; off >>= 1) s += __shfl_xor(s, off);
    if ((threadIdx.x & 63) == 0) red[threadIdx.x >> 6] = s;
    __syncthreads();
    float tot = red[0] + red[1] + red[2] + red[3];
    __syncthreads();
    return tot;
}

// 4 independent block-wide sums (one per row-of-4-group) in one pass.
__device__ __forceinline__ float4 block_sum4(float4 s) {
    __shared__ __align__(16) float red4[4][4];
    #pragma unroll
    for (int off = 32; off; off >>= 1) {
        s.x += __shfl_xor(s.x, off);
        s.y += __shfl_xor(s.y, off);
        s.z += __shfl_xor(s.z, off);
        s.w += __shfl_xor(s.w, off);
    }
    if ((threadIdx.x & 63) == 0) *(float4*)red4[threadIdx.x >> 6] = s;
    __syncthreads();
    float4 t;
    t.x = red4[0][0] + red4[1][0] + red4[2][0] + red4[3][0];
    t.y = red4[0][1] + red4[1][1] + red4[2][1] + red4[3][1];
    t.z = red4[0][2] + red4[1][2] + red4[2][2] + red4[3][2];
    t.w = red4[0][3] + red4[1][3] + red4[2][3] + red4[3][3];
    __syncthreads();
    return t;
}

// ---------------------------------------------------------------------------
// MEGA: self-attn + wo + LN + cross(q-proj, attn, cwo) + LN.
// G=4 rows of the SAME batch per block: grid (B_, ceil(P/4)); rows
// r_g = (p0+g)*B + b. Amortizes wo/cwq/cwo (3 MB) and v/Vc/KcT reads 4x.
// Weight loops stay ROW-MAJOR float2 (wave-coalesced 2KB segments) —
// transposed per-lane streams measured +8ms (uncoalesced).
// ---------------------------------------------------------------------------
__global__ __launch_bounds__(256) void attn_mega_k(
    const float* __restrict__ q, const float* __restrict__ kT,
    const float* __restrict__ v, const float* __restrict__ wo,
    const float* __restrict__ KcT, const float* __restrict__ Vc,
    const float* __restrict__ cmask, const float* __restrict__ cwq,
    const float* __restrict__ cwo, float* __restrict__ x,
    const float* __restrict__ lg, const float* __restrict__ lb, int P)
{
    int b = blockIdx.x;
    int p0 = blockIdx.y * 4;
    int tid = threadIdx.x;
    int c0 = tid * 2;
    __shared__ float xs[4][D_];
    __shared__ float arow[4][D_];
    __shared__ float scs[4][H_][SENC + 4];
    __shared__ float inv[4][H_];
    // ---- stage q rows into arow (invalid rows -> 0)
    #pragma unroll
    for (int g = 0; g < 4; g++) {
        float2 qv = make_float2(0.f, 0.f);
        if (p0 + g < P)
            qv = *(const float2*)&q[((size_t)(p0 + g) * B_ + b) * D_ + c0];
        *(float2*)&arow[g][c0] = qv;
    }
    __syncthreads();
    // ---- self scores: thread (h=tid>>5, kp=tid&31), 4 rows per thread
    {
        int h = tid >> 5, kp = tid & 31;
        float a0 = 0.f, a1 = 0.f, a2 = 0.f, a3 = 0.f;
        if (kp < P) {
            const float* kb = kT + ((size_t)(b * 8 + h) * 64) * TP1 + kp;
            #pragma unroll 8
            for (int d = 0; d < 64; d++) {
                float kv = kb[(size_t)d * TP1];
                a0 += arow[0][h * 64 + d] * kv;
                a1 += arow[1][h * 64 + d] * kv;
                a2 += arow[2][h * 64 + d] * kv;
                a3 += arow[3][h * 64 + d] * kv;
            }
        }
        scs[0][h][kp] = a0 * 0.125f;
        scs[1][h][kp] = a1 * 0.125f;
        scs[2][h][kp] = a2 * 0.125f;
        scs[3][h][kp] = a3 * 0.125f;
    }
    __syncthreads();
    // ---- self softmax: 32 (g,h) groups x 8 lanes, shuffle reduce
    {
        int gh = tid >> 3, lane8 = tid & 7;
        int g = gh >> 3, h = gh & 7;
        float mx = -1e30f;
        for (int j = lane8; j < P; j += 8) mx = fmaxf(mx, scs[g][h][j]);
        mx = fmaxf(mx, __shfl_xor(mx, 1));
        mx = fmaxf(mx, __shfl_xor(mx, 2));
        mx = fmaxf(mx, __shfl_xor(mx, 4));
        float sum = 0.f;
        for (int j = lane8; j < P; j += 8) {
            float e = expf(scs[g][h][j] - mx);
            scs[g][h][j] = e;
            sum += e;
        }
        sum += __shfl_xor(sum, 1);
        sum += __shfl_xor(sum, 2);
        sum += __shfl_xor(sum, 4);
        if (lane8 == 0) inv[g][h] = 1.f / sum;
    }
    __syncthreads();
    // ---- self weighted V -> arow (v row shared by all 4 g: same batch b)
    {
        int h = tid >> 5;
        float o0[4] = {0.f, 0.f, 0.f, 0.f}, o1[4] = {0.f, 0.f, 0.f, 0.f};
        for (int j = 0; j < P; j++) {
            float2 vv = *(const float2*)&v[((size_t)j * B_ + b) * D_ + c0];
            #pragma unroll
            for (int g = 0; g < 4; g++) {
                float w = scs[g][h][j];
                o0[g] += w * vv.x; o1[g] += w * vv.y;
            }
        }
        #pragma unroll
        for (int g = 0; g < 4; g++) {
            arow[g][c0]     = o0[g] * inv[g][h];
            arow[g][c0 + 1] = o1[g] * inv[g][h];
        }
    }
    __syncthreads();
    // ---- wo out-proj + residual + LN -> xs (8 FMA per 8B weight read)
    {
        float v0[4], v1[4];
        #pragma unroll
        for (int g = 0; g < 4; g++) {
            float2 xv = make_float2(0.f, 0.f);
            if (p0 + g < P)
                xv = *(const float2*)&x[((size_t)(p0 + g) * B_ + b) * D_ + c0];
            v0[g] = xv.x; v1[g] = xv.y;
        }
        #pragma unroll 8
        for (int k = 0; k < D_; k++) {
            float2 wv = *(const float2*)&wo[(size_t)k * D_ + c0];
            #pragma unroll
            for (int g = 0; g < 4; g++) {
                float a = arow[g][k];
                v0[g] += a * wv.x; v1[g] += a * wv.y;
            }
        }
        float4 s1 = make_float4(v0[0] + v1[0], v0[1] + v1[1],
                                v0[2] + v1[2], v0[3] + v1[3]);
        float4 m4 = block_sum4(s1);
        float mean[4] = {m4.x * (1.f / 512.f), m4.y * (1.f / 512.f),
                         m4.z * (1.f / 512.f), m4.w * (1.f / 512.f)};
        float d0[4], d1[4];
        #pragma unroll
        for (int g = 0; g < 4; g++) {
            d0[g] = v0[g] - mean[g]; d1[g] = v1[g] - mean[g];
        }
        float4 s2 = make_float4(d0[0] * d0[0] + d1[0] * d1[0],
                                d0[1] * d0[1] + d1[1] * d1[1],
                                d0[2] * d0[2] + d1[2] * d1[2],
                                d0[3] * d0[3] + d1[3] * d1[3]);
        float4 w4 = block_sum4(s2);
        float var[4] = {w4.x * (1.f / 512.f), w4.y * (1.f / 512.f),
                        w4.z * (1.f / 512.f), w4.w * (1.f / 512.f)};
        float g0 = lg[c0], g1 = lg[c0 + 1];
        float bb0 = lb[c0], bb1 = lb[c0 + 1];
        #pragma unroll
        for (int g = 0; g < 4; g++) {
            float rs = rsqrtf(var[g] + EPSV);
            xs[g][c0]     = d0[g] * rs * g0 + bb0;
            xs[g][c0 + 1] = d1[g] * rs * g1 + bb1;
        }
    }
    __syncthreads();
    // ---- cross q-proj -> arow
    {
        float q0[4] = {0.f, 0.f, 0.f, 0.f}, q1[4] = {0.f, 0.f, 0.f, 0.f};
        #pragma unroll 8
        for (int k = 0; k < D_; k++) {
            float2 wv = *(const float2*)&cwq[(size_t)k * D_ + c0];
            #pragma unroll
            for (int g = 0; g < 4; g++) {
                float a = xs[g][k];
                q0[g] += a * wv.x; q1[g] += a * wv.y;
            }
        }
        #pragma unroll
        for (int g = 0; g < 4; g++) {
            arow[g][c0] = q0[g]; arow[g][c0 + 1] = q1[g];
        }
    }
    __syncthreads();
    // ---- cross scores: 4 (h,s) pairs per thread, 4 rows each
    #pragma unroll
    for (int i = 0; i < 4; i++) {
        int idx = tid + i * 256;
        int h = idx >> 7, s = idx & 127;
        const float* kb = KcT + ((size_t)(b * 512 + h * 64)) * SENC + s;
        float a0 = 0.f, a1 = 0.f, a2 = 0.f, a3 = 0.f;
        #pragma unroll 8
        for (int d = 0; d < 64; d++) {
            float kc = kb[(size_t)d * SENC];
            a0 += arow[0][h * 64 + d] * kc;
            a1 += arow[1][h * 64 + d] * kc;
            a2 += arow[2][h * 64 + d] * kc;
            a3 += arow[3][h * 64 + d] * kc;
        }
        float cm = cmask[b * SENC + s];
        scs[0][h][s] = a0 * 0.125f + cm;
        scs[1][h][s] = a1 * 0.125f + cm;
        scs[2][h][s] = a2 * 0.125f + cm;
        scs[3][h][s] = a3 * 0.125f + cm;
    }
    __syncthreads();
    // ---- cross softmax
    {
        int gh = tid >> 3, lane8 = tid & 7;
        int g = gh >> 3, h = gh & 7;
        float mx = -1e30f;
        for (int s = lane8; s < SENC; s += 8) mx = fmaxf(mx, scs[g][h][s]);
        mx = fmaxf(mx, __shfl_xor(mx, 1));
        mx = fmaxf(mx, __shfl_xor(mx, 2));
        mx = fmaxf(mx, __shfl_xor(mx, 4));
        float sum = 0.f;
        for (int s = lane8; s < SENC; s += 8) {
            float e = expf(scs[g][h][s] - mx);
            scs[g][h][s] = e;
            sum += e;
        }
        sum += __shfl_xor(sum, 1);
        sum += __shfl_xor(sum, 2);
        sum += __shfl_xor(sum, 4);
        if (lane8 == 0) inv[g][h] = 1.f / sum;
    }
    __syncthreads();
    // ---- cross weighted V -> arow (Vc rows shared across g)
    {
        int h = tid >> 5;
        float o0[4] = {0.f, 0.f, 0.f, 0.f}, o1[4] = {0.f, 0.f, 0.f, 0.f};
        for (int s = 0; s < SENC; s++) {
            float2 vv = *(const float2*)&Vc[((size_t)b * SENC + s) * D_ + c0];
            #pragma unroll
            for (int g = 0; g < 4; g++) {
                float w = scs[g][h][s];
                o0[g] += w * vv.x; o1[g] += w * vv.y;
            }
        }
        #pragma unroll
        for (int g = 0; g < 4; g++) {
            arow[g][c0]     = o0[g] * inv[g][h];
            arow[g][c0 + 1] = o1[g] * inv[g][h];
        }
    }
    __syncthreads();
    // ---- cwo out-proj + residual(xs) + LN -> x (guarded stores)
    {
        float v0[4], v1[4];
        #pragma unroll
        for (int g = 0; g < 4; g++) {
            v0[g] = xs[g][c0]; v1[g] = xs[g][c0 + 1];
        }
        #pragma unroll 8
        for (int k = 0; k < D_; k++) {
            float2 wv = *(const float2*)&cwo[(size_t)k * D_ + c0];
            #pragma unroll
            for (int g = 0; g < 4; g++) {
                float a = arow[g][k];
                v0[g] += a * wv.x; v1[g] += a * wv.y;
            }
        }
        float4 s1 = make_float4(v0[0] + v1[0], v0[1] + v1[1],
                                v0[2] + v1[2], v0[3] + v1[3]);
        float4 m4 = block_sum4(s1);
        float mean[4] = {m4.x * (1.f / 512.f), m4.y * (1.f / 512.f),
                         m4.z * (1.f / 512.f), m4.w * (1.f / 512.f)};
        float d0[4], d1[4];
        #pragma unroll
        for (int g = 0; g < 4; g++) {
            d0[g] = v0[g] - mean[g]; d1[g] = v1[g] - mean[g];
        }
        float4 s2 = make_float4(d0[0] * d0[0] + d1[0] * d1[0],
                                d0[1] * d0[1] + d1[1] * d1[1],
                                d0[2] * d0[2] + d1[2] * d1[2],
                                d0[3] * d0[3] + d1[3] * d1[3]);
        float4 w4 = block_sum4(s2);
        float var[4] = {w4.x * (1.f / 512.f), w4.y * (1.f / 512.f),
                        w4.z * (1.f / 512.f), w4.w * (1.f / 512.f)};
        float g0 = lg[D_ + c0], g1 = lg[D_ + c0 + 1];
        float bb0 = lb[D_ + c0], bb1 = lb[D_ + c0 + 1];
        #pragma unroll
        for (int g = 0; g < 4; g++) {
            if (p0 + g < P) {
                float rs = rsqrtf(var[g] + EPSV);
                float* xr = x + ((size_t)(p0 + g) * B_ + b) * D_;
                xr[c0]     = d0[g] * rs * g0 + bb0;
                xr[c0 + 1] = d1[g] * rs * g1 + bb1;
            }
        }
    }
}

// ---------------------------------------------------------------------------
// x = LN(x + sum_parts (+ bias)) * g + b. One block per row.
// ---------------------------------------------------------------------------
__global__ __launch_bounds__(256) void ln_red_k(
    float* __restrict__ x, const float* __restrict__ parts, size_t pstride,
    int nparts, const float* __restrict__ bias,
    const float* __restrict__ gam, const float* __restrict__ bet)
{
    int r = blockIdx.x;
    float* xr = x + (size_t)r * D_;
    int tid = threadIdx.x;
    float v0 = xr[tid];
    float v1 = xr[tid + 256];
    for (int s = 0; s < nparts; s++) {
        const float* pr = parts + (size_t)s * pstride + (size_t)r * D_;
        v0 += pr[tid];
        v1 += pr[tid + 256];
    }
    if (bias) { v0 += bias[tid]; v1 += bias[tid + 256]; }
    float mean = block_sum(v0 + v1) * (1.f / 512.f);
    float d0 = v0 - mean, d1 = v1 - mean;
    float var = block_sum(d0 * d0 + d1 * d1) * (1.f / 512.f);
    float rs = rsqrtf(var + EPSV);
    xr[tid]       = d0 * rs * gam[tid] + bet[tid];
    xr[tid + 256] = d1 * rs * gam[tid + 256] + bet[tid + 256];
}

// ---------------------------------------------------------------------------
// logits -> per-block argmax candidates. Grid 125 x 256 thr = 64 cols x
// 4 K-chunks; wave 0 reduces its 64 cols per batch (val,idx).
// ---------------------------------------------------------------------------
__global__ __launch_bounds__(256) void logits_k(
    const float* __restrict__ x, const float* __restrict__ fcw,
    const float* __restrict__ fcb, float* __restrict__ cand_v,
    int* __restrict__ cand_i, int t)
{
    __shared__ float xs[B_][D_];
    __shared__ float red[4][64][B_];
    int tid = threadIdx.x;
    for (int i = tid; i < B_ * D_; i += 256) {
        int b = i >> 9, d = i & 511;
        xs[b][d] = x[((size_t)t * B_ + b) * D_ + d];
    }
    __syncthreads();
    int lane = tid & 63, ks = tid >> 6;
    int col = blockIdx.x * 64 + lane;
    float acc[B_] = {};
    int kb = ks * 128;
    for (int k = kb; k < kb + 128; k++) {
        float w = fcw[(size_t)k * V_ + col];
        #pragma unroll
        for (int b = 0; b < B_; b++) acc[b] += xs[b][k] * w;
    }
    #pragma unroll
    for (int b = 0; b < B_; b++) red[ks][lane][b] = acc[b];
    __syncthreads();
    if (ks == 0) {      // wave 0 only
        float bias = fcb[col];
        #pragma unroll
        for (int b = 0; b < B_; b++) {
            float val = red[0][lane][b] + red[1][lane][b]
                      + red[2][lane][b] + red[3][lane][b] + bias;
            int idx = col;
            #pragma unroll
            for (int off = 32; off; off >>= 1) {
                float ov = __shfl_down(val, off);
                int oi = __shfl_down(idx, off);
                if (ov > val || (ov == val && oi < idx)) { val = ov; idx = oi; }
            }
            if (lane == 0) {
                cand_v[(size_t)b * 125 + blockIdx.x] = val;
                cand_i[(size_t)b * 125 + blockIdx.x] = idx;
            }
        }
    }
}

// ---------------------------------------------------------------------------
// Final: one block per batch. Reduce step-31 candidates for token 32, copy
// the output row.
// ---------------------------------------------------------------------------
__global__ __launch_bounds__(128) void writeout_k(
    const int* __restrict__ tokens, const float* __restrict__ cand_v,
    const int* __restrict__ cand_i, const int* __restrict__ done,
    int* __restrict__ out)
{
    int b = blockIdx.x;
    int tid = threadIdx.x;
    __shared__ float sv[128];
    __shared__ int si[128];
    __shared__ int stok;
    float val = -1e30f; int idx = 0x7fffffff;
    if (tid < 125) {
        val = cand_v[(size_t)b * 125 + tid];
        idx = cand_i[(size_t)b * 125 + tid];
    }
    sv[tid] = val; si[tid] = idx;
    __syncthreads();
    for (int s = 64; s; s >>= 1) {
        if (tid < s) {
            float ov = sv[tid + s]; int oi = si[tid + s];
            if (ov > sv[tid] || (ov == sv[tid] && oi < si[tid])) {
                sv[tid] = ov; si[tid] = oi;
            }
        }
        __syncthreads();
    }
    if (tid == 0) {
        int best = si[0];
        int dn = done[b] | (best == 2 ? 1 : 0);
        stok = dn ? 0 : best;
    }
    __syncthreads();
    if (tid < T_)
        out[b * T_ + tid] = (tid == T_ - 1) ? stok : tokens[b * TP1 + tid + 1];
}

// ---------------------------------------------------------------------------
extern "C" void kernel_launch(void* const* d_in, const int* in_sizes, int n_in,
                              void* d_out, int out_size, void* d_ws, size_t ws_size,
                              hipStream_t stream)
{
    const float* enc   = (const float*)d_in[1];
    const float* pm    = (const float*)d_in[2];
    const float* embed = (const float*)d_in[3];
    const float* wq    = (const float*)d_in[4];
    const float* wk    = (const float*)d_in[5];
    const float* wv    = (const float*)d_in[6];
    const float* wo    = (const float*)d_in[7];
    const float* cwq   = (const float*)d_in[8];
    const float* cwk   = (const float*)d_in[9];
    const float* cwv   = (const float*)d_in[10];
    const float* cwo   = (const float*)d_in[11];
    const float* w1    = (const float*)d_in[12];
    const float* b1    = (const float*)d_in[13];
    const float* w2    = (const float*)d_in[14];
    const float* b2    = (const float*)d_in[15];
    const float* ln_g  = (const float*)d_in[16];
    const float* ln_b  = (const float*)d_in[17];
    const float* fcw   = (const float*)d_in[18];
    const float* fcb   = (const float*)d_in[19];

    float* ws = (float*)d_ws;
    size_t off = 0;
    float* x     = ws + off; off += XSZ;
    float* qkv   = ws + off; off += 3 * XSZ;      // q | kT | v
    float* parts = ws + off; off += 4 * XSZ;      // split-K partials
    float* ffnh  = ws + off; off += (size_t)TP1 * B_ * DFF_;
    float* cand_v= ws + off; off += (size_t)B_ * 125;
    float* KcT   = ws + off; off += (size_t)L_ * B_ * SENC * D_;
    float* Vc    = ws + off; off += (size_t)L_ * B_ * SENC * D_;
    float* cmask = ws + off; off += (size_t)B_ * SENC;
    float* pe    = ws + off; off += (size_t)TP1 * D_;
    int* cand_i  = (int*)(ws + off); off += (size_t)B_ * 125;
    int* tokens  = (int*)(ws + off); off += (B_ * TP1 + 63) & ~63;
    int* done    = (int*)(ws + off); off += 64;

    init_k<<<8, 256, 0, stream>>>(tokens, done, cmask, pm);
    pe_k<<<TP1, 256, 0, stream>>>(pe);

    // Precompute cross K (transposed) / V per layer
    const size_t KVL = (size_t)B_ * SENC * D_;
    for (int l = 0; l < L_; l++) {
        gemm32_k<<<dim3(8, (B_ * SENC) / 32), 256, 0, stream>>>(
            enc, cwk + (size_t)l * D_ * D_, nullptr, KcT + l * KVL,
            B_ * SENC, D_, D_, D_, 0, 0, 1);
        gemm32_k<<<dim3(8, (B_ * SENC) / 32), 256, 0, stream>>>(
            enc, cwv + (size_t)l * D_ * D_, nullptr, Vc + l * KVL,
            B_ * SENC, D_, D_, D_, 0, 0, 0);
    }

    for (int t = 0; t < T_; t++) {
        int P = t + 1;
        int M = P * B_;
        int mt = (M + 31) / 32;

        embed_k<<<dim3(P, B_), 256, 0, stream>>>(
            embed, tokens, x, pe, cand_v, cand_i, done, t);

        for (int l = 0; l < L_; l++) {
            const size_t lw = (size_t)l * D_ * D_;
            gemm_qkv_k<<<dim3(24, mt), 256, 0, stream>>>(
                x, wq + lw, wk + lw, wv + lw, qkv, M);
            attn_mega_k<<<dim3(B_, (P + 3) / 4), 256, 0, stream>>>(
                qkv, qkv + XSZ, qkv + 2 * XSZ, wo + lw,
                KcT + l * KVL, Vc + l * KVL, cmask, cwq + lw, cwo + lw, x,
                ln_g + (size_t)(l * 3 + 0) * D_, ln_b + (size_t)(l * 3 + 0) * D_, P);
            gemm32_k<<<dim3(32, mt), 256, 0, stream>>>(
                x, w1 + (size_t)l * D_ * DFF_, b1 + (size_t)l * DFF_, ffnh,
                M, DFF_, D_, D_, 0, 1, 0);
            gemm32_k<<<dim3(8, mt, 4), 256, 0, stream>>>(
                ffnh, w2 + (size_t)l * DFF_ * D_, nullptr, parts,
                M, D_, DFF_, 512, XSZ, 0, 0);
            ln_red_k<<<M, 256, 0, stream>>>(x, parts, XSZ, 4, b2 + (size_t)l * D_,
                ln_g + (size_t)(l * 3 + 2) * D_, ln_b + (size_t)(l * 3 + 2) * D_);
        }

        logits_k<<<V_ / 64, 256, 0, stream>>>(x, fcw, fcb, cand_v, cand_i, t);
    }

    writeout_k<<<B_, 128, 0, stream>>>(tokens, cand_v, cand_i, done, (int*)d_out);
}